// Round 8
// baseline (72.674 us; speedup 1.0000x reference)
//
#include <hip/hip_runtime.h>
#include <hip/hip_bf16.h>
#include <stdint.h>
#include <math.h>

#define BB 8
#define SS 8192
#define NN 16
#define DD 64
#define MM 64
#define TS 32    // s-rows per LDS tile
#define PAD 40   // row stride (bf16): 80 B, 16B-aligned rows; reads 2-way (free), writes 8-way (accepted)

typedef __attribute__((ext_vector_type(8))) short bf16x8;
typedef __attribute__((ext_vector_type(4))) float f32x4;

__device__ __forceinline__ float feat(float x) {
    // elu(x) + 1 == x+1 (x>0), exp(x) (x<=0); feat(-inf) = 0 (masked rows)
    return x > 0.0f ? (x + 1.0f) : __expf(x);
}

// One v_cvt_pk_bf16_f32: packs {bf16(hi), bf16(lo)} into a u32 (RNE).
// No builtin on gfx950; non-volatile asm so the scheduler may reorder it.
__device__ __forceinline__ uint32_t cvt_pk_bf16(float lo, float hi) {
    uint32_t r;
    asm("v_cvt_pk_bf16_f32 %0, %1, %2" : "=v"(r) : "v"(lo), "v"(hi));
    return r;
}

// Raw barrier (no vmcnt drain): sched_barrier pins LDS ops above, the
// explicit lgkmcnt(0) makes this wave's ds_writes visible, s_barrier syncs
// arrival. Global loads issued earlier stay IN FLIGHT across it (T4).
#define SYNCW()                                        \
    do {                                               \
        __builtin_amdgcn_sched_barrier(0);             \
        asm volatile("s_waitcnt lgkmcnt(0)");          \
        __builtin_amdgcn_s_barrier();                  \
        __builtin_amdgcn_sched_barrier(0);             \
    } while (0)

struct Slot {
    float4 kq0, kq1, vq0, vq1;
};

__device__ __forceinline__ void load_tile(Slot& s, int ti, uint32_t bits,
                                          const float* kb, const float* vb,
                                          int sl, int c0) {
    const bool lv0 = !((bits >> (2 * ti)) & 1);
    const bool lv1 = !((bits >> (2 * ti + 1)) & 1);
    // masked K rows preset to -inf -> feat() yields 0 with no predication;
    // masked V rows stay 0 (K=0 makes their MFMA contribution 0 anyway).
    const float ninf = -INFINITY;
    s.kq0 = make_float4(ninf, ninf, ninf, ninf);
    s.kq1 = make_float4(ninf, ninf, ninf, ninf);
    s.vq0 = make_float4(0.f, 0.f, 0.f, 0.f);
    s.vq1 = make_float4(0.f, 0.f, 0.f, 0.f);
    const size_t s0 = (size_t)(ti * TS + sl);
    if (lv0) {
        s.kq0 = *reinterpret_cast<const float4*>(kb + s0 * (NN * DD) + c0);
        s.vq0 = *reinterpret_cast<const float4*>(vb + s0 * (NN * MM) + c0);
    }
    if (lv1) {
        s.kq1 = *reinterpret_cast<const float4*>(kb + (s0 + 1) * (NN * DD) + c0);
        s.vq1 = *reinterpret_cast<const float4*>(vb + (s0 + 1) * (NN * MM) + c0);
    }
}

__device__ __forceinline__ void stage_tile(const Slot& s, float* zacc,
                                           __hip_bfloat16 (*Kbuf)[PAD],
                                           __hip_bfloat16 (*Vbuf)[PAD],
                                           int c0, int sl) {
    const float sk0[4] = {s.kq0.x, s.kq0.y, s.kq0.z, s.kq0.w};
    const float sk1[4] = {s.kq1.x, s.kq1.y, s.kq1.z, s.kq1.w};
    const float sv0[4] = {s.vq0.x, s.vq0.y, s.vq0.z, s.vq0.w};
    const float sv1[4] = {s.vq1.x, s.vq1.y, s.vq1.z, s.vq1.w};
    #pragma unroll
    for (int j = 0; j < 4; ++j) {
        const float fk0 = feat(sk0[j]);   // masked -> feat(-inf) = 0
        const float fk1 = feat(sk1[j]);
        zacc[j] += fk0 + fk1;
        const uint32_t pk = cvt_pk_bf16(fk0, fk1);       // 1 inst, 2 elems
        const uint32_t pv = cvt_pk_bf16(sv0[j], sv1[j]); // 1 inst, 2 elems
        *reinterpret_cast<uint32_t*>(&Kbuf[c0 + j][sl]) = pk;
        *reinterpret_cast<uint32_t*>(&Vbuf[c0 + j][sl]) = pv;
    }
}

__device__ __forceinline__ void mfma_step(const __hip_bfloat16 (*Kbuf)[PAD],
                                          const __hip_bfloat16 (*Vbuf)[PAD],
                                          f32x4& acc00, f32x4& acc01,
                                          f32x4& acc10, f32x4& acc11,
                                          int wm, int wd, int g, int lr) {
    const bf16x8 fa0 = *reinterpret_cast<const bf16x8*>(&Vbuf[wm + lr][g * 8]);
    const bf16x8 fa1 = *reinterpret_cast<const bf16x8*>(&Vbuf[wm + 16 + lr][g * 8]);
    const bf16x8 fb0 = *reinterpret_cast<const bf16x8*>(&Kbuf[wd + lr][g * 8]);
    const bf16x8 fb1 = *reinterpret_cast<const bf16x8*>(&Kbuf[wd + 16 + lr][g * 8]);
    acc00 = __builtin_amdgcn_mfma_f32_16x16x32_bf16(fa0, fb0, acc00, 0, 0, 0);
    acc01 = __builtin_amdgcn_mfma_f32_16x16x32_bf16(fa0, fb1, acc01, 0, 0, 0);
    acc10 = __builtin_amdgcn_mfma_f32_16x16x32_bf16(fa1, fb0, acc10, 0, 0, 0);
    acc11 = __builtin_amdgcn_mfma_f32_16x16x32_bf16(fa1, fb1, acc11, 0, 0, 0);
}

// One block per (bn, chunk). 256 threads = 4 waves; wave w owns the 32x32
// output quadrant (wm, wd) of Sst[64][64]. LDS tiles stored transposed
// (Kl[d][s], Vl[m][s], bf16) so each MFMA fragment is one ds_read_b128.
// Pipeline: depth-2 register prefetch (slots sA/sB) + double-buffered LDS +
// ONE raw barrier per tile; loads never cross a draining barrier.
__global__ __launch_bounds__(256)
void rcla_partial(const float* __restrict__ key,
                  const float* __restrict__ value,
                  const int* __restrict__ mask,
                  float* __restrict__ ws, int C) {
    const int blk = blockIdx.x;
    const int c  = blk % C;
    const int bn = blk / C;
    const int b  = bn >> 4;   // N = 16
    const int n  = bn & 15;
    const int t  = threadIdx.x;

    // staging mapping: thread t handles columns c0..c0+3 of rows sl, sl+1
    const int a  = t & 15;
    const int p  = t >> 4;        // 0..15
    const int c0 = a << 2;        // d (K) / m (V)
    const int sl = p << 1;        // local s (even)

    // MFMA mapping
    const int lane = t & 63;
    const int w    = t >> 6;
    const int wm   = (w >> 1) << 5;
    const int wd   = (w & 1) << 5;
    const int g    = lane >> 4;   // s-octet of the fragment
    const int lr   = lane & 15;

    __shared__ __align__(16) __hip_bfloat16 Kl[2][DD][PAD];   // 10240 B
    __shared__ __align__(16) __hip_bfloat16 Vl[2][MM][PAD];   // 10240 B -> 20480 total

    const int steps   = SS / C;      // 512 at C=16
    const int nt      = steps / TS;  // 16 (even; 2*nt <= 32 bits)
    const int s_begin = c * steps;

    const float* kb = key   + (((size_t)b * SS) * NN + n) * DD + (size_t)s_begin * (NN * DD);
    const float* vb = value + (((size_t)b * SS) * NN + n) * MM + (size_t)s_begin * (NN * MM);
    const int*   mb = mask  + (size_t)b * SS + s_begin;

    // per-thread mask bits: this thread only ever touches rows sl, sl+1
    uint32_t bits = 0;
    for (int i = 0; i < nt; ++i) {
        bits |= (uint32_t)(mb[i * TS + sl]     != 0) << (2 * i);
        bits |= (uint32_t)(mb[i * TS + sl + 1] != 0) << (2 * i + 1);
    }

    f32x4 acc00 = {}, acc01 = {}, acc10 = {}, acc11 = {};
    float zacc[4] = {0.f, 0.f, 0.f, 0.f};

    Slot sA, sB;
    load_tile(sA, 0, bits, kb, vb, sl, c0);
    load_tile(sB, 1, bits, kb, vb, sl, c0);

    // Hazard ledger (1 barrier/tile): every LDS write-after-read pair
    // (stage_tile(x, buf) vs previous mfma_step(buf)) is separated by
    // exactly one SYNCW arrival barrier; all LDS ops are lgkm-waited
    // before barrier entry.
    for (int ti = 0; ti < nt; ti += 2) {
        stage_tile(sA, zacc, Kl[0], Vl[0], c0, sl);
        if (ti + 2 < nt) load_tile(sA, ti + 2, bits, kb, vb, sl, c0);
        SYNCW();
        mfma_step(Kl[0], Vl[0], acc00, acc01, acc10, acc11, wm, wd, g, lr);

        stage_tile(sB, zacc, Kl[1], Vl[1], c0, sl);
        if (ti + 3 < nt) load_tile(sB, ti + 3, bits, kb, vb, sl, c0);
        SYNCW();
        mfma_step(Kl[1], Vl[1], acc00, acc01, acc10, acc11, wm, wd, g, lr);
    }

    // partials: 4096 Sst + 64 Z per (bn, c)
    float* out = ws + ((size_t)bn * C + c) * 4160;

    // C/D layout: col = lane&15, row = (lane>>4)*4 + reg
    #pragma unroll
    for (int r = 0; r < 4; ++r) {
        out[(wm + g * 4 + r) * DD + wd + lr]           = acc00[r];
        out[(wm + g * 4 + r) * DD + wd + 16 + lr]      = acc01[r];
        out[(wm + 16 + g * 4 + r) * DD + wd + lr]      = acc10[r];
        out[(wm + 16 + g * 4 + r) * DD + wd + 16 + lr] = acc11[r];
    }

    // Z reduction: reuse Kl[0] as float scratch (fenced by __syncthreads).
    __syncthreads();
    float* Zf = reinterpret_cast<float*>(&Kl[0][0][0]);   // [16][64] floats
    *reinterpret_cast<float4*>(&Zf[p * DD + c0]) =
        make_float4(zacc[0], zacc[1], zacc[2], zacc[3]);
    __syncthreads();
    if (t < DD) {
        float z = 0.f;
        #pragma unroll
        for (int q = 0; q < 16; ++q) z += Zf[q * DD + t];
        out[4096 + t] = z;
    }
}

// One block per (bn, m-quarter): reduce C partials for 16 m-rows, emit Sst
// (and Z from quarter 0), then QZ and V.
__global__ __launch_bounds__(256)
void rcla_final(const float* __restrict__ query,
                const float* __restrict__ ws, int C,
                float* __restrict__ outV, float* __restrict__ outS,
                float* __restrict__ outZ) {
    const int q   = blockIdx.x & 3;
    const int bn  = blockIdx.x >> 2;
    const int t   = threadIdx.x;
    const int d0  = (t & 15) << 2;
    const int mr  = (q << 4) + (t >> 4);
    const float* p0 = ws + (size_t)bn * C * 4160;

    float sst[4] = {0.f, 0.f, 0.f, 0.f};
    float z[4]   = {0.f, 0.f, 0.f, 0.f};

    for (int c = 0; c < C; ++c) {
        const float* p = p0 + (size_t)c * 4160;
        const float4 v = *reinterpret_cast<const float4*>(p + mr * DD + d0);
        sst[0] += v.x; sst[1] += v.y; sst[2] += v.z; sst[3] += v.w;
        const float4 zv = *reinterpret_cast<const float4*>(p + 4096 + d0);
        z[0] += zv.x; z[1] += zv.y; z[2] += zv.z; z[3] += zv.w;
    }

    *reinterpret_cast<float4*>(outS + (size_t)bn * 4096 + mr * DD + d0) =
        make_float4(sst[0], sst[1], sst[2], sst[3]);
    if (q == 0 && t < 16) {
        *reinterpret_cast<float4*>(outZ + (size_t)bn * DD + d0) =
            make_float4(z[0], z[1], z[2], z[3]);
    }

    float qf[4];
    #pragma unroll
    for (int j = 0; j < 4; ++j) qf[j] = feat(query[(size_t)bn * DD + d0 + j]);

    float pd = qf[0]*z[0] + qf[1]*z[1] + qf[2]*z[2] + qf[3]*z[3];
    float pv = qf[0]*sst[0] + qf[1]*sst[1] + qf[2]*sst[2] + qf[3]*sst[3];
    #pragma unroll
    for (int off = 1; off < 16; off <<= 1) {
        pd += __shfl_xor(pd, off);
        pv += __shfl_xor(pv, off);
    }
    if ((t & 15) == 0) {
        const float qz = 1.0f / (pd + 1e-6f);
        outV[(size_t)bn * MM + mr] = qz * pv;
    }
}

extern "C" void kernel_launch(void* const* d_in, const int* in_sizes, int n_in,
                              void* d_out, int out_size, void* d_ws, size_t ws_size,
                              hipStream_t stream) {
    const float* query = (const float*)d_in[0];
    const float* key   = (const float*)d_in[1];
    const float* value = (const float*)d_in[2];
    const int*   mask  = (const int*)d_in[3];

    float* out  = (float*)d_out;
    float* outV = out;                         // [B,N,M]   8192
    float* outS = out + BB * NN * MM;          // [B,N,M,D] 524288
    float* outZ = outS + BB * NN * MM * DD;    // [B,N,D]   8192
    float* ws   = (float*)d_ws;

    int C = 16;   // 2048 blocks -> 8 blocks/CU (32 waves/CU)
    while (C > 8 && (size_t)BB * NN * C * 4160 * sizeof(float) > ws_size) C >>= 1;

    rcla_partial<<<dim3(BB * NN * C), dim3(256), 0, stream>>>(key, value, mask, ws, C);
    rcla_final<<<dim3(BB * NN * 4), dim3(256), 0, stream>>>(query, ws, C, outV, outS, outZ);
}

// Round 9
// 68.664 us; speedup vs baseline: 1.0584x; 1.0584x over previous
//
#include <hip/hip_runtime.h>
#include <hip/hip_bf16.h>
#include <stdint.h>
#include <math.h>

#define BB 8
#define SS 8192
#define NN 16
#define DD 64
#define MM 64
#define TS 32    // s-rows per LDS tile
#define PAD 40   // row stride (bf16): 80 B; b128 writes/reads both hit all 32 banks (8 lanes/quad = optimal)

typedef __attribute__((ext_vector_type(8))) short bf16x8;
typedef __attribute__((ext_vector_type(4))) float f32x4;

__device__ __forceinline__ float feat(float x) {
    // elu(x) + 1 == x+1 (x>0), exp(x) (x<=0); feat(-inf) = 0 (masked rows)
    return x > 0.0f ? (x + 1.0f) : __expf(x);
}

// One v_cvt_pk_bf16_f32: packs {bf16(hi), bf16(lo)} into a u32 (RNE).
__device__ __forceinline__ uint32_t cvt_pk_bf16(float lo, float hi) {
    uint32_t r;
    asm("v_cvt_pk_bf16_f32 %0, %1, %2" : "=v"(r) : "v"(lo), "v"(hi));
    return r;
}

// 4x4 cross-lane u32 transpose on the VALU pipe (not LDS):
// in:  x[j] on lane-group q (groups of 16) = D(row j, col q)
// out: x[j] on lane-group q = D(row q, col j)
// Stage 1: block swap over bit1 (permlane32_swap: vdst[32:63] <-> vsrc[0:31])
// Stage 2: within-half swap over bit0 (permlane16_swap: odd-16 rows of vdst
//          <-> even-16 rows of vsrc). Element-wise traced for correctness.
__device__ __forceinline__ void xpose4(uint32_t& x0, uint32_t& x1,
                                       uint32_t& x2, uint32_t& x3) {
    asm("v_permlane32_swap_b32 %0, %1" : "+v"(x0), "+v"(x2));
    asm("v_permlane32_swap_b32 %0, %1" : "+v"(x1), "+v"(x3));
    asm("v_permlane16_swap_b32 %0, %1" : "+v"(x0), "+v"(x1));
    asm("v_permlane16_swap_b32 %0, %1" : "+v"(x2), "+v"(x3));
}

// Raw barrier (no vmcnt drain): global loads stay in flight across it (T4).
#define SYNCW()                                        \
    do {                                               \
        __builtin_amdgcn_sched_barrier(0);             \
        asm volatile("s_waitcnt lgkmcnt(0)");          \
        __builtin_amdgcn_s_barrier();                  \
        __builtin_amdgcn_sched_barrier(0);             \
    } while (0)

struct Slot {
    float4 kq0, kq1, vq0, vq1;
};

__device__ __forceinline__ void load_tile(Slot& s, int ti, uint32_t bits,
                                          const float* kb, const float* vb,
                                          int sl, int c0) {
    const bool lv0 = !((bits >> (2 * ti)) & 1);
    const bool lv1 = !((bits >> (2 * ti + 1)) & 1);
    // masked K rows preset to -inf -> feat() yields 0 with no predication;
    // masked V rows stay 0 (K=0 zeroes their MFMA contribution anyway).
    const float ninf = -INFINITY;
    s.kq0 = make_float4(ninf, ninf, ninf, ninf);
    s.kq1 = make_float4(ninf, ninf, ninf, ninf);
    s.vq0 = make_float4(0.f, 0.f, 0.f, 0.f);
    s.vq1 = make_float4(0.f, 0.f, 0.f, 0.f);
    const size_t s0 = (size_t)(ti * TS + sl);
    if (lv0) {
        s.kq0 = *reinterpret_cast<const float4*>(kb + s0 * (NN * DD) + c0);
        s.vq0 = *reinterpret_cast<const float4*>(vb + s0 * (NN * MM) + c0);
    }
    if (lv1) {
        s.kq1 = *reinterpret_cast<const float4*>(kb + (s0 + 1) * (NN * DD) + c0);
        s.vq1 = *reinterpret_cast<const float4*>(vb + (s0 + 1) * (NN * MM) + c0);
    }
}

// Stage: feat + cvt_pk (VALU) -> 4x4 permlane transpose (VALU) -> ONE
// ds_write_b128 per tensor per thread (conflict-optimal), replacing 4
// 8-way-conflicted u32 writes. Lane (a,q) of wave w writes row 4a+q,
// s-octet w.
__device__ __forceinline__ void stage_tile(const Slot& s, float* zacc,
                                           __hip_bfloat16 (*Kbuf)[PAD],
                                           __hip_bfloat16 (*Vbuf)[PAD],
                                           int c0, int q, int woct) {
    const float sk0[4] = {s.kq0.x, s.kq0.y, s.kq0.z, s.kq0.w};
    const float sk1[4] = {s.kq1.x, s.kq1.y, s.kq1.z, s.kq1.w};
    const float sv0[4] = {s.vq0.x, s.vq0.y, s.vq0.z, s.vq0.w};
    const float sv1[4] = {s.vq1.x, s.vq1.y, s.vq1.z, s.vq1.w};
    uint32_t xk[4], xv[4];
    #pragma unroll
    for (int j = 0; j < 4; ++j) {
        const float fk0 = feat(sk0[j]);   // masked -> feat(-inf) = 0
        const float fk1 = feat(sk1[j]);
        zacc[j] += fk0 + fk1;
        xk[j] = cvt_pk_bf16(fk0, fk1);
        xv[j] = cvt_pk_bf16(sv0[j], sv1[j]);
    }
    xpose4(xk[0], xk[1], xk[2], xk[3]);
    xpose4(xv[0], xv[1], xv[2], xv[3]);
    const int row = c0 + q;   // c0 = 4a
    *reinterpret_cast<uint4*>(&Kbuf[row][woct * 8]) = make_uint4(xk[0], xk[1], xk[2], xk[3]);
    *reinterpret_cast<uint4*>(&Vbuf[row][woct * 8]) = make_uint4(xv[0], xv[1], xv[2], xv[3]);
}

__device__ __forceinline__ void mfma_step(const __hip_bfloat16 (*Kbuf)[PAD],
                                          const __hip_bfloat16 (*Vbuf)[PAD],
                                          f32x4& acc00, f32x4& acc01,
                                          f32x4& acc10, f32x4& acc11,
                                          int wm, int wd, int g, int lr) {
    const bf16x8 fa0 = *reinterpret_cast<const bf16x8*>(&Vbuf[wm + lr][g * 8]);
    const bf16x8 fa1 = *reinterpret_cast<const bf16x8*>(&Vbuf[wm + 16 + lr][g * 8]);
    const bf16x8 fb0 = *reinterpret_cast<const bf16x8*>(&Kbuf[wd + lr][g * 8]);
    const bf16x8 fb1 = *reinterpret_cast<const bf16x8*>(&Kbuf[wd + 16 + lr][g * 8]);
    acc00 = __builtin_amdgcn_mfma_f32_16x16x32_bf16(fa0, fb0, acc00, 0, 0, 0);
    acc01 = __builtin_amdgcn_mfma_f32_16x16x32_bf16(fa0, fb1, acc01, 0, 0, 0);
    acc10 = __builtin_amdgcn_mfma_f32_16x16x32_bf16(fa1, fb0, acc10, 0, 0, 0);
    acc11 = __builtin_amdgcn_mfma_f32_16x16x32_bf16(fa1, fb1, acc11, 0, 0, 0);
}

// One block per (bn, chunk). 256 threads = 4 waves; wave w owns the 32x32
// output quadrant (wm, wd) of Sst[64][64] and stages s-octet w of each tile.
// LDS tiles transposed (Kl[d][s], Vl[m][s], bf16); fragments = ds_read_b128.
// Pipeline: depth-2 register prefetch + double-buffered LDS + one raw
// barrier per tile (loads never cross a draining barrier).
__global__ __launch_bounds__(256)
void rcla_partial(const float* __restrict__ key,
                  const float* __restrict__ value,
                  const int* __restrict__ mask,
                  float* __restrict__ ws, int C) {
    const int blk = blockIdx.x;
    const int c  = blk % C;
    const int bn = blk / C;
    const int b  = bn >> 4;   // N = 16
    const int n  = bn & 15;
    const int t  = threadIdx.x;

    // staging mapping: thread t handles d/m-cols c0..c0+3 of s-rows sl, sl+1
    const int a  = t & 15;
    const int p  = t >> 4;        // 0..15 block-wide; = 4*wave + q
    const int c0 = a << 2;        // d (K) / m (V)
    const int sl = p << 1;        // local s (even)
    const int q  = p & 3;         // lane-group within wave
    const int woct = p >> 2;      // = wave id = s-octet staged by this wave

    // MFMA mapping
    const int lane = t & 63;
    const int w    = t >> 6;
    const int wm   = (w >> 1) << 5;
    const int wd   = (w & 1) << 5;
    const int g    = lane >> 4;   // s-octet of the fragment
    const int lr   = lane & 15;

    __shared__ __align__(16) __hip_bfloat16 Kl[2][DD][PAD];   // 10240 B
    __shared__ __align__(16) __hip_bfloat16 Vl[2][MM][PAD];   // 10240 B -> 20480 total

    const int steps   = SS / C;      // 512 at C=16
    const int nt      = steps / TS;  // 16 (even; 2*nt <= 32 bits)
    const int s_begin = c * steps;

    const float* kb = key   + (((size_t)b * SS) * NN + n) * DD + (size_t)s_begin * (NN * DD);
    const float* vb = value + (((size_t)b * SS) * NN + n) * MM + (size_t)s_begin * (NN * MM);
    const int*   mb = mask  + (size_t)b * SS + s_begin;

    // per-thread mask bits: this thread only ever touches rows sl, sl+1
    uint32_t bits = 0;
    for (int i = 0; i < nt; ++i) {
        bits |= (uint32_t)(mb[i * TS + sl]     != 0) << (2 * i);
        bits |= (uint32_t)(mb[i * TS + sl + 1] != 0) << (2 * i + 1);
    }

    f32x4 acc00 = {}, acc01 = {}, acc10 = {}, acc11 = {};
    float zacc[4] = {0.f, 0.f, 0.f, 0.f};

    Slot sA, sB;
    load_tile(sA, 0, bits, kb, vb, sl, c0);
    load_tile(sB, 1, bits, kb, vb, sl, c0);

    // Hazard ledger (1 barrier/tile): every LDS write-after-read pair
    // (stage_tile(x, buf) vs previous mfma_step(buf)) is separated by
    // exactly one SYNCW arrival barrier; all LDS ops lgkm-waited before
    // barrier entry.
    for (int ti = 0; ti < nt; ti += 2) {
        stage_tile(sA, zacc, Kl[0], Vl[0], c0, q, woct);
        if (ti + 2 < nt) load_tile(sA, ti + 2, bits, kb, vb, sl, c0);
        SYNCW();
        mfma_step(Kl[0], Vl[0], acc00, acc01, acc10, acc11, wm, wd, g, lr);

        stage_tile(sB, zacc, Kl[1], Vl[1], c0, q, woct);
        if (ti + 3 < nt) load_tile(sB, ti + 3, bits, kb, vb, sl, c0);
        SYNCW();
        mfma_step(Kl[1], Vl[1], acc00, acc01, acc10, acc11, wm, wd, g, lr);
    }

    // partials: 4096 Sst + 64 Z per (bn, c)
    float* out = ws + ((size_t)bn * C + c) * 4160;

    // C/D layout: col = lane&15, row = (lane>>4)*4 + reg
    #pragma unroll
    for (int r = 0; r < 4; ++r) {
        out[(wm + g * 4 + r) * DD + wd + lr]           = acc00[r];
        out[(wm + g * 4 + r) * DD + wd + 16 + lr]      = acc01[r];
        out[(wm + 16 + g * 4 + r) * DD + wd + lr]      = acc10[r];
        out[(wm + 16 + g * 4 + r) * DD + wd + 16 + lr] = acc11[r];
    }

    // Z reduction: reuse Kl[0] as float scratch (fenced by __syncthreads).
    __syncthreads();
    float* Zf = reinterpret_cast<float*>(&Kl[0][0][0]);   // [16][64] floats
    *reinterpret_cast<float4*>(&Zf[p * DD + c0]) =
        make_float4(zacc[0], zacc[1], zacc[2], zacc[3]);
    __syncthreads();
    if (t < DD) {
        float z = 0.f;
        #pragma unroll
        for (int qq = 0; qq < 16; ++qq) z += Zf[qq * DD + t];
        out[4096 + t] = z;
    }
}

// One block per (bn, m-quarter): reduce C partials for 16 m-rows, emit Sst
// (and Z from quarter 0), then QZ and V.
__global__ __launch_bounds__(256)
void rcla_final(const float* __restrict__ query,
                const float* __restrict__ ws, int C,
                float* __restrict__ outV, float* __restrict__ outS,
                float* __restrict__ outZ) {
    const int q   = blockIdx.x & 3;
    const int bn  = blockIdx.x >> 2;
    const int t   = threadIdx.x;
    const int d0  = (t & 15) << 2;
    const int mr  = (q << 4) + (t >> 4);
    const float* p0 = ws + (size_t)bn * C * 4160;

    float sst[4] = {0.f, 0.f, 0.f, 0.f};
    float z[4]   = {0.f, 0.f, 0.f, 0.f};

    for (int c = 0; c < C; ++c) {
        const float* p = p0 + (size_t)c * 4160;
        const float4 v = *reinterpret_cast<const float4*>(p + mr * DD + d0);
        sst[0] += v.x; sst[1] += v.y; sst[2] += v.z; sst[3] += v.w;
        const float4 zv = *reinterpret_cast<const float4*>(p + 4096 + d0);
        z[0] += zv.x; z[1] += zv.y; z[2] += zv.z; z[3] += zv.w;
    }

    *reinterpret_cast<float4*>(outS + (size_t)bn * 4096 + mr * DD + d0) =
        make_float4(sst[0], sst[1], sst[2], sst[3]);
    if (q == 0 && t < 16) {
        *reinterpret_cast<float4*>(outZ + (size_t)bn * DD + d0) =
            make_float4(z[0], z[1], z[2], z[3]);
    }

    float qf[4];
    #pragma unroll
    for (int j = 0; j < 4; ++j) qf[j] = feat(query[(size_t)bn * DD + d0 + j]);

    float pd = qf[0]*z[0] + qf[1]*z[1] + qf[2]*z[2] + qf[3]*z[3];
    float pv = qf[0]*sst[0] + qf[1]*sst[1] + qf[2]*sst[2] + qf[3]*sst[3];
    #pragma unroll
    for (int off = 1; off < 16; off <<= 1) {
        pd += __shfl_xor(pd, off);
        pv += __shfl_xor(pv, off);
    }
    if ((t & 15) == 0) {
        const float qz = 1.0f / (pd + 1e-6f);
        outV[(size_t)bn * MM + mr] = qz * pv;
    }
}

extern "C" void kernel_launch(void* const* d_in, const int* in_sizes, int n_in,
                              void* d_out, int out_size, void* d_ws, size_t ws_size,
                              hipStream_t stream) {
    const float* query = (const float*)d_in[0];
    const float* key   = (const float*)d_in[1];
    const float* value = (const float*)d_in[2];
    const int*   mask  = (const int*)d_in[3];

    float* out  = (float*)d_out;
    float* outV = out;                         // [B,N,M]   8192
    float* outS = out + BB * NN * MM;          // [B,N,M,D] 524288
    float* outZ = outS + BB * NN * MM * DD;    // [B,N,D]   8192
    float* ws   = (float*)d_ws;

    int C = 16;   // 2048 blocks -> 8 blocks/CU (32 waves/CU)
    while (C > 8 && (size_t)BB * NN * C * 4160 * sizeof(float) > ws_size) C >>= 1;

    rcla_partial<<<dim3(BB * NN * C), dim3(256), 0, stream>>>(key, value, mask, ws, C);
    rcla_final<<<dim3(BB * NN * 4), dim3(256), 0, stream>>>(query, ws, C, outV, outS, outZ);
}